// Round 10
// baseline (111.019 us; speedup 1.0000x reference)
//
#include <hip/hip_runtime.h>
#include <math.h>

#define NS 2000
#define NPAD 2048
#define EPS_F 1.1920928955078125e-07f
#define BLOCK 512
#define WAVES (BLOCK / 64)        // 8 waves per block
#define EPW 2                     // elements per wave (shared LDS stream)
#define LOG2E 1.4426950408889634f
#define MAGICF 12582912.0f        // 1.5 * 2^23
#define EXPC (127 - 0x4B400000)   // bits(t) + EXPC == exponent field of 2^n

// Taylor coefficients for 2^f on [-0.5, 0.5] (rel err ~1.2e-7)
#define K1 0.69314718055994531f
#define K2 0.24022650695910071f
#define K3 0.055504108664821580f
#define K4 0.0096181291076284772f
#define K5 0.0013333558146428443f
#define K6 0.00015403530393381610f

typedef float v2f __attribute__((ext_vector_type(2)));

// Packed fp32 ops (gfx90a+ v_pk_*_f32). Compiler won't auto-emit; asm it.
static __device__ __forceinline__ v2f pk_add(v2f a, v2f b) {
    v2f d; asm("v_pk_add_f32 %0, %1, %2" : "=v"(d) : "v"(a), "v"(b)); return d;
}
static __device__ __forceinline__ v2f pk_mul(v2f a, v2f b) {
    v2f d; asm("v_pk_mul_f32 %0, %1, %2" : "=v"(d) : "v"(a), "v"(b)); return d;
}
static __device__ __forceinline__ v2f pk_fma(v2f a, v2f b, v2f c) {
    v2f d; asm("v_pk_fma_f32 %0, %1, %2, %3" : "=v"(d) : "v"(a), "v"(b), "v"(c)); return d;
}

// Packed 2^z for z <= ~13.5; deep-negative z clamps to 2^-126 (~1.2e-38,
// negligible vs per-element sums >= 1). Clamp BEFORE the magic trick so
// garbage-f (|z| ~ 1e15 at sigma ~ EPS) can never reach the poly (no inf*0).
static __device__ __forceinline__ v2f pk_exp2(v2f z) {
    z.x = fmaxf(z.x, -126.0f);
    z.y = fmaxf(z.y, -126.0f);
    const v2f magic = {MAGICF, MAGICF};
    const v2f nmagic = {-MAGICF, -MAGICF};
    const v2f neg1 = {-1.0f, -1.0f};
    v2f t = pk_add(z, magic);
    v2f nf = pk_add(t, nmagic);          // nf = round-to-nearest-int(z)
    v2f f = pk_fma(nf, neg1, z);         // f = z - nf, in [-0.5, 0.5]
    const v2f c6 = {K6, K6}, c5 = {K5, K5}, c4 = {K4, K4};
    const v2f c3 = {K3, K3}, c2 = {K2, K2}, c1 = {K1, K1};
    const v2f one = {1.0f, 1.0f};
    v2f p = pk_fma(c6, f, c5);
    p = pk_fma(p, f, c4);
    p = pk_fma(p, f, c3);
    p = pk_fma(p, f, c2);
    p = pk_fma(p, f, c1);
    p = pk_fma(p, f, one);
    int ex = (__float_as_int(t.x) + EXPC) << 23;   // 2^n exponent bits
    int ey = (__float_as_int(t.y) + EXPC) << 23;
    v2f sc = {__int_as_float(ex), __int_as_float(ey)};
    return pk_mul(p, sc);
}

// Scalar twin: bit-identical op sequence per lane-half (fma chains match
// the packed halves exactly) so coop/epilogue q's equal pass-1 q's.
static __device__ __forceinline__ float s_exp2(float z) {
    z = fmaxf(z, -126.0f);
    float t = z + MAGICF;
    float nf = t - MAGICF;
    float f = fmaf(nf, -1.0f, z);
    float p = fmaf(K6, f, K5);
    p = fmaf(p, f, K4);
    p = fmaf(p, f, K3);
    p = fmaf(p, f, K2);
    p = fmaf(p, f, K1);
    p = fmaf(p, f, 1.0f);
    int e = (__float_as_int(t) + EXPC) << 23;
    return p * __int_as_float(e);
}

// DPP scan helpers (verified rounds 7-9): old=0, bound_ctrl=1.
template <int CTRL, int RMASK>
static __device__ __forceinline__ float dpp_add(float x) {
    int t = __builtin_amdgcn_update_dpp(0, __float_as_int(x), CTRL, RMASK, 0xf, true);
    return x + __int_as_float(t);
}
static __device__ __forceinline__ float scan64(float x) {
    x = dpp_add<0x111, 0xf>(x);
    x = dpp_add<0x112, 0xf>(x);
    x = dpp_add<0x114, 0xf>(x);
    x = dpp_add<0x118, 0xf>(x);
    x = dpp_add<0x142, 0xa>(x);   // row_bcast:15 -> rows 1,3
    x = dpp_add<0x143, 0xc>(x);   // row_bcast:31 -> rows 2,3
    return x;
}
static __device__ __forceinline__ float scan32(float x) {
    x = dpp_add<0x111, 0xf>(x);
    x = dpp_add<0x112, 0xf>(x);
    x = dpp_add<0x114, 0xf>(x);
    x = dpp_add<0x118, 0xf>(x);
    x = dpp_add<0x142, 0xa>(x);
    return x;
}
static __device__ __forceinline__ float bcast_lane(float x, int lane_sgpr) {
    return __int_as_float(__builtin_amdgcn_readlane(__float_as_int(x), lane_sgpr));
}

// Kernel 1: build table views.
//   tabT (float4/slot kk*64+l): (a_{2kk}, a_{2kk+1}, lw_{2kk}, lw_{2kk+1})
//     of lane l's points 32l+2kk, 32l+2kk+1  -> packed-pair pass 1.
//   tab2 (float2, linear): (a, lw) -> coop re-eval + epilogue.
// a = atanh grid value, lw = log2(1/(1-x^2)); pads lw=-1000 => q ~ 0.
__global__ void build_table(float* __restrict__ tabT, float2* __restrict__ tab2) {
    int i = blockIdx.x * blockDim.x + threadIdx.x;
    if (i >= NPAD) return;
    float a = 0.0f, lw = -1000.0f;
    if (i < NS) {
        const double y0 = -0.9999, y1 = 0.9999;
        const double step = (y1 - y0) / 1999.0;
        float x = (i == NS - 1) ? (float)y1 : (float)(y0 + (double)i * step);
        float ratio = (1.0f + x) / (1.0f - x) + EPS_F;   // ref: (1+x)/(1-x)+EPS
        a = 0.5f * logf(ratio);                          // atanh_x
        float w = 1.0f / (1.0f - x * x);                 // 1/(1-x^2), >= 1
        lw = log2f(w);
    }
    tab2[i] = make_float2(a, lw);
    int l = i >> 5, k = i & 31, kk = k >> 1, h = k & 1;
    int s = kk * 64 + l;
    tabT[s * 4 + h] = a;
    tabT[s * 4 + 2 + h] = lw;
}

// Per-element selection + write (scalar path; called twice, fully inlined).
static __device__ __forceinline__ void finish(
    int elem, int lane, float s, float negmu, float rd2, float nc, float u,
    const float2* __restrict__ sP, float* __restrict__ ov, float* __restrict__ op) {
    float incl = scan64(s);
    const float S = bcast_lane(incl, 63);          // wave-uniform q-sum
    const float denom = S * nc + EPS_F;            // ref: sum(probs)+EPS
    const float tt = (u * denom) / nc;             // threshold in q-space

    unsigned long long mgt = __ballot(incl > tt);
    int jstar = mgt ? __builtin_ctzll(mgt) : 64;
    int jj = (jstar < 64) ? jstar : 0;
    float exclb = bcast_lane(incl - s, jj);        // exclusive chunk offset

    // Cooperative re-eval of chunk jj (both 32-lane halves duplicate;
    // same-address LDS reads broadcast, conflict-free).
    int c = lane & 31;
    float2 al = sP[jj * 32 + c];
    float d = al.x + negmu;
    float cum = scan32(s_exp2(fmaf(d * d, rd2, al.y)));
    cum += exclb;
    unsigned int m2 = (unsigned int)(__ballot(cum > tt) & 0xffffffffULL);
    int sub = m2 ? (int)__builtin_ctz(m2) : 32;
    int idx = (jstar >= 64) ? 0 : min(jj * 32 + sub, NS - 1);

    if (lane == 0) {
        float2 a2 = sP[idx];
        float dd = a2.x + negmu;
        float pk = s_exp2(fmaf(dd * dd, rd2, a2.y)) * nc;
        const double y0 = -0.9999, y1 = 0.9999;
        const double step = (y1 - y0) / 1999.0;
        float gv = (idx == NS - 1) ? (float)y1 : (float)(y0 + (double)idx * step);
        ov[elem] = gv;
        op[elem] = pk / denom;                     // ref: probs/(sum+EPS)
    }
}

// Kernel 2: one wave handles EPW=2 consecutive elements against a single
// LDS table stream. Pass 1 evaluates q = 2^((a-mu)^2*rd2 + lw) with the
// PACKED polynomial exp2 (v_pk ops, 2 points per chain) -- removes the
// v_exp_f32 issue-pipe occupancy that bounded rounds 4-9.
__global__ __launch_bounds__(BLOCK) void sample_kernel(
    const float* __restrict__ mean, const float* __restrict__ stdv,
    const float* __restrict__ uni, const float4* __restrict__ gT,
    const float4* __restrict__ gP,
    float* __restrict__ out_vals, float* __restrict__ out_probs, int nElem) {
    __shared__ float4 sT[NPAD / 2];     // pair view (16 KB)
    __shared__ float4 sPb[NPAD / 2];    // linear view (16 KB)
    const float2* sP = (const float2*)sPb;
    for (int t = threadIdx.x; t < NPAD / 2; t += BLOCK) {
        sT[t] = gT[t];
        sPb[t] = gP[t];
    }
    __syncthreads();

    const int lane = threadIdx.x & 63;
    const int wid = threadIdx.x >> 6;
    const int e0 = (blockIdx.x * WAVES + wid) * EPW;
    if (e0 >= nElem) return;

    // Header (wave-uniform element params).
    const float muA = mean[e0], muB = mean[e0 + 1];
    const float sgA = stdv[e0] + EPS_F, sgB = stdv[e0 + 1] + EPS_F;
    const float uA = uni[e0], uB = uni[e0 + 1];
    const float sg2A = sgA * sgA, sg2B = sgB * sgB;
    const float rd2A = LOG2E / (-2.0f * sg2A);
    const float rd2B = LOG2E / (-2.0f * sg2B);
    const float ncA = 1.0f / sqrtf(6.2831853071795864f * sg2A);
    const float ncB = 1.0f / sqrtf(6.2831853071795864f * sg2B);

    const v2f nmuA = {-muA, -muA}, nmuB = {-muB, -muB};
    const v2f rdA = {rd2A, rd2A}, rdB = {rd2B, rd2B};

    // Pass 1: packed-pair evaluation, both elements share each LDS read.
    v2f accA = {0.0f, 0.0f}, accB = {0.0f, 0.0f};
    #pragma unroll
    for (int kk = 0; kk < 16; kk++) {
        float4 v = sT[kk * 64 + lane];             // (a0,a1,lw0,lw1)
        v2f ap = {v.x, v.y};
        v2f lwp = {v.z, v.w};
        v2f dA = pk_add(ap, nmuA);
        v2f zA = pk_fma(pk_mul(dA, dA), rdA, lwp);
        accA = pk_add(accA, pk_exp2(zA));
        v2f dB = pk_add(ap, nmuB);
        v2f zB = pk_fma(pk_mul(dB, dB), rdB, lwp);
        accB = pk_add(accB, pk_exp2(zB));
    }

    finish(e0,     lane, accA.x + accA.y, -muA, rd2A, ncA, uA, sP, out_vals, out_probs);
    finish(e0 + 1, lane, accB.x + accB.y, -muB, rd2B, ncB, uB, sP, out_vals, out_probs);
}

extern "C" void kernel_launch(void* const* d_in, const int* in_sizes, int n_in,
                              void* d_out, int out_size, void* d_ws, size_t ws_size,
                              hipStream_t stream) {
    const float* mean = (const float*)d_in[0];
    const float* stdv = (const float*)d_in[1];
    const float* uni = (const float*)d_in[2];
    float* out = (float*)d_out;
    const int nElem = in_sizes[0];                 // 4096*16 = 65536
    float* out_vals = out;
    float* out_probs = out + nElem;

    float* tabT = (float*)d_ws;                    // 4096 f32 = 16 KB
    float2* tab2 = (float2*)(tabT + 2 * NPAD);     // 2048 float2 = 16 KB

    build_table<<<NPAD / 256, 256, 0, stream>>>(tabT, tab2);

    const int elemsPerBlock = WAVES * EPW;         // 16
    const int grid = (nElem + elemsPerBlock - 1) / elemsPerBlock;  // 4096
    sample_kernel<<<grid, BLOCK, 0, stream>>>(mean, stdv, uni,
                                              (const float4*)tabT,
                                              (const float4*)tab2,
                                              out_vals, out_probs, nElem);
}

// Round 13
// 75.648 us; speedup vs baseline: 1.4676x; 1.4676x over previous
//
#include <hip/hip_runtime.h>
#include <math.h>

#define NS 2000
#define NPAD 2048
#define EPS_F 1.1920928955078125e-07f
#define LOG2E 1.4426950408889634f
#define X0F  -0.9999f
#define HREC 999.64996f            // 1/h, h = 1.9998/1999
#define HF   1.00040020e-3f        // h
#define B8C  2.7842747f            // atanh(-0.9999 + 7.5h), bulk/edge seam
#define SIGM 2.0e-3f               // sigma >= 2*h*cosh^2 => sigma/h_loc >= 2
#define PCELL_MIN 1.0e-4f          // min normalized crossing-cell mass (bulk)
#define FLIP_TOL 0.012f            // max output-1 impact of a +-1 index flip

// 2^x via v_exp_f32 (named wrapper: __exp2f collides with glibc math.h).
__device__ __forceinline__ float exp2_hw(float x) {
    return __builtin_amdgcn_exp2f(x);
}

// ---------- DPP scan helpers (verified rounds 7-9) ----------
template <int CTRL, int RMASK>
static __device__ __forceinline__ float dpp_add(float x) {
    int t = __builtin_amdgcn_update_dpp(0, __float_as_int(x), CTRL, RMASK, 0xf, true);
    return x + __int_as_float(t);
}
static __device__ __forceinline__ float scan64(float x) {
    x = dpp_add<0x111, 0xf>(x);
    x = dpp_add<0x112, 0xf>(x);
    x = dpp_add<0x114, 0xf>(x);
    x = dpp_add<0x118, 0xf>(x);
    x = dpp_add<0x142, 0xa>(x);   // row_bcast:15 -> rows 1,3
    x = dpp_add<0x143, 0xc>(x);   // row_bcast:31 -> rows 2,3
    return x;
}
static __device__ __forceinline__ float scan32(float x) {
    x = dpp_add<0x111, 0xf>(x);
    x = dpp_add<0x112, 0xf>(x);
    x = dpp_add<0x114, 0xf>(x);
    x = dpp_add<0x118, 0xf>(x);
    x = dpp_add<0x142, 0xa>(x);
    return x;
}
static __device__ __forceinline__ float bcast_lane(float x, int lane_sgpr) {
    return __int_as_float(__builtin_amdgcn_readlane(__float_as_int(x), lane_sgpr));
}

// ---------- scalar special functions ----------
// Phi(t) = 0.5*erfc(-t/sqrt2), erfc via A&S 7.1.26 (|err| <= 1.5e-7 abs).
static __device__ __forceinline__ float cdf01(float t) {
    float z = -t * 0.70710678f;
    float az = fabsf(z);
    float k = 1.0f / fmaf(0.3275911f, az, 1.0f);
    float poly = fmaf(k, 1.061405429f, -1.453152027f);
    poly = fmaf(k, poly, 1.421413741f);
    poly = fmaf(k, poly, -0.284496736f);
    poly = fmaf(k, poly, 0.254829592f);
    poly *= k;
    float e = exp2_hw(-az * az * LOG2E);       // exp(-z^2)
    float erfc_az = poly * e;
    float erfc_z = (z < 0.0f) ? (2.0f - erfc_az) : erfc_az;
    return 0.5f * erfc_z;
}
// Giles single-precision erfinv.
static __device__ __forceinline__ float erfinv_f(float x) {
    float w = -logf(fmaf(-x, x, 1.0f));
    bool c = w < 5.0f;
    float ww = c ? (w - 2.5f) : (sqrtf(w) - 3.0f);
    float p = c ? 2.81022636e-08f : -0.000200214257f;
    p = fmaf(p, ww, c ? 3.43273939e-07f : 0.000100950558f);
    p = fmaf(p, ww, c ? -3.5233877e-06f : 0.00134934322f);
    p = fmaf(p, ww, c ? -4.39150654e-06f : -0.00367342844f);
    p = fmaf(p, ww, c ? 0.00021858087f : 0.00573950773f);
    p = fmaf(p, ww, c ? -0.00125372503f : -0.0076224613f);
    p = fmaf(p, ww, c ? -0.00417768164f : 0.00943887047f);
    p = fmaf(p, ww, c ? 0.246640727f : 1.00167406f);
    p = fmaf(p, ww, c ? 1.50140941f : 2.83297682f);
    return p * x;
}
static __device__ __forceinline__ float cosh2f(float t) {    // cosh^2(|t|)
    float e = exp2_hw(2.8853901f * t);                       // e^{2t}
    float re = __builtin_amdgcn_rcpf(e);
    return 0.25f * (e + 2.0f + re);
}

// ---------- Kernel 1: tables (r8 layout) + clear fallback counter ----------
__global__ void build_table(float2* __restrict__ tabT, float2* __restrict__ tab2,
                            int* __restrict__ cnt) {
    int i = blockIdx.x * blockDim.x + threadIdx.x;
    if (i == 0) *cnt = 0;
    if (i >= NPAD) return;
    float a = 0.0f, lw = -1000.0f;
    if (i < NS) {
        const double y0 = -0.9999, y1 = 0.9999;
        const double step = (y1 - y0) / 1999.0;
        float x = (i == NS - 1) ? (float)y1 : (float)(y0 + (double)i * step);
        float ratio = (1.0f + x) / (1.0f - x) + EPS_F;   // ref: (1+x)/(1-x)+EPS
        a = 0.5f * logf(ratio);                          // atanh_x
        float w = 1.0f / (1.0f - x * x);                 // 1/(1-x^2)
        lw = log2f(w);
    }
    tab2[i] = make_float2(a, lw);
    int l = i >> 5, k = i & 31, kk = k >> 1, h = k & 1;
    tabT[(kk * 64 + l) * 2 + h] = make_float2(a, lw);
}

// ---------- Kernel 2: hybrid analytic, one THREAD per element ----------
// 8 coarsest cells each end summed EXACTLY; bulk via continuous CDF.
// Crossing: exact low-edge walk; guarded erfinv inversion in bulk.
// High-edge / no-crossing / flip-sensitive elements -> exact fallback.
__global__ __launch_bounds__(256) void analytic_kernel(
    const float* __restrict__ mean, const float* __restrict__ stdv,
    const float* __restrict__ uni, const float2* __restrict__ tab2,
    float* __restrict__ out_vals, float* __restrict__ out_probs,
    int* __restrict__ list, int* __restrict__ cnt, int nElem) {
    int gid = blockIdx.x * blockDim.x + threadIdx.x;
    if (gid >= nElem) return;

    const float mu = mean[gid];
    const float sg = stdv[gid] + EPS_F;          // ref: std + EPS
    const float u = uni[gid];
    const float inv_sg = 1.0f / sg;
    const float rd2 = -0.72134752f * inv_sg * inv_sg;   // log2e/(-2 s^2)
    const float nc = 0.39894228f * inv_sg;              // 1/sqrt(2pi s^2)
    const float hn = HF * nc;

    // Exact edge cells (q-units).
    float ql[8];
    float qlow = 0.0f, qhigh = 0.0f;
    #pragma unroll
    for (int c = 0; c < 8; c++) {
        float2 al = tab2[c];
        float d = al.x - mu;
        ql[c] = exp2_hw(fmaf(d * d, rd2, al.y));
        qlow += ql[c];
        float2 ah = tab2[NS - 8 + c];
        float dh = ah.x - mu;
        qhigh += exp2_hw(fmaf(dh * dh, rd2, ah.y));
    }

    const float PloB = cdf01((-B8C - mu) * inv_sg);
    const float PhiB = cdf01(( B8C - mu) * inv_sg);
    const float Qbulk = fmaxf(PhiB - PloB, 0.0f) / hn;   // q-units
    const float Stot = qlow + Qbulk + qhigh;
    const float denomP = fmaf(nc, Stot, EPS_F);          // ref: sum(probs)+EPS
    const float tt = u * denomP / nc;                    // target, q-units

    // Seam/peak fine-ness guard (Qbulk enters Stot for every path).
    bool ok = (sg >= SIGM * cosh2f(fminf(fabsf(mu), B8C)));
    // High-edge crossing or no-crossing: base would inherit Qbulk's error
    // against tiny edge cells (multi-cell flips) -> exact fallback.
    ok = ok && (tt < qlow + Qbulk);

    int idx = -1;
    float qsel = 0.0f;

    // Low-edge exact walk (exact q's, exact running sum).
    {
        float cum = 0.0f;
        #pragma unroll
        for (int c = 0; c < 8; c++) {
            cum += ql[c];
            if (idx < 0 && cum > tt) { idx = c; qsel = ql[c]; }
        }
    }
    if (ok && idx < 0) {
        // Bulk inversion: Phi_target -> a* -> x index.
        float Pt = fmaf(tt - qlow, hn, PloB);
        float xx = fmaf(2.0f, Pt, -1.0f);
        xx = fminf(fmaxf(xx, -0.99999994f), 0.99999994f);
        float ts = 1.41421356f * erfinv_f(xx);
        float as = fmaf(sg, ts, mu);
        float e2 = exp2_hw(as * 2.8853901f);         // e^{2a*}
        float tau = 1.0f - 2.0f / (e2 + 1.0f);       // tanh(a*)
        float fi = fmaf(tau - X0F, HREC, -0.5f);
        int is = (int)floorf(fi) + 1;
        ok = ok && (is >= 8) && (is <= 1991)
                && (sg >= SIGM * cosh2f(fabsf(as)));
        is = min(max(is, 8), 1991);
        float2 al = tab2[is];
        float d = al.x - mu;
        float qi = exp2_hw(fmaf(d * d, rd2, al.y));
        float pn = nc * qi / denomP;                 // normalized cell mass
        ok = ok && (pn >= PCELL_MIN);                // inversion stability
        // Flip-impact guard: a +-1 index flip must move output-1 by <=
        // FLIP_TOL. Adjacent-cell prob ratio = exp(hl*|z|/sg + hl^2/2sg^2).
        float hl = HF * cosh2f(fabsf(as));           // local a-spacing
        float r = hl * inv_sg;
        float arg = r * (fabsf(as - mu) * inv_sg + 0.5f * r);
        float ratio = exp2_hw(LOG2E * fminf(arg, 20.0f)) - 1.0f;
        ok = ok && (pn * ratio <= FLIP_TOL);
        if (ok) { idx = is; qsel = qi; }
    }

    if (ok && idx >= 0) {
        const double y0 = -0.9999, y1 = 0.9999;
        const double step = (y1 - y0) / 1999.0;
        float gv = (idx == NS - 1) ? (float)y1 : (float)(y0 + (double)idx * step);
        out_vals[gid] = gv;
        out_probs[gid] = nc * qsel / denomP;             // ref: p/(sum+EPS)
    } else {
        int slot = atomicAdd(cnt, 1);
        list[slot] = gid;
    }
}

// ---------- Kernel 3: exact fallback, wave-per-element (r8 verbatim) ------
__global__ __launch_bounds__(256) void fallback_kernel(
    const float* __restrict__ mean, const float* __restrict__ stdv,
    const float* __restrict__ uni, const float4* __restrict__ gT,
    const float4* __restrict__ gP,
    float* __restrict__ out_vals, float* __restrict__ out_probs,
    const int* __restrict__ list, const int* __restrict__ cnt) {
    const int count = *cnt;
    if (blockIdx.x * 4 >= count) return;    // idle blocks: exit before fill

    __shared__ float4 sT[NPAD / 2];
    __shared__ float4 sPbuf[NPAD / 2];
    const float2* sP = (const float2*)sPbuf;
    for (int t = threadIdx.x; t < NPAD / 2; t += 256) {
        sT[t] = gT[t];
        sPbuf[t] = gP[t];
    }
    __syncthreads();

    const int lane = threadIdx.x & 63;
    const int wid = threadIdx.x >> 6;
    const int stride = gridDim.x << 2;

    for (int slot = blockIdx.x * 4 + wid; slot < count; slot += stride) {
        const int elem = list[slot];
        const float mu = mean[elem];
        const float sg = stdv[elem] + EPS_F;           // ref: std + EPS
        const float u = uni[elem];
        const float sg2 = sg * sg;
        const float rden2 = LOG2E / (-2.0f * sg2);
        const float normc = 1.0f / sqrtf(6.2831853071795864f * sg2);

        float s0 = 0.0f, s1 = 0.0f;
        #pragma unroll
        for (int kk = 0; kk < 16; kk++) {
            float4 v = sT[kk * 64 + lane];             // (a0,lw0,a1,lw1)
            float d0 = v.x - mu;
            s0 += exp2_hw(fmaf(d0 * d0, rden2, v.y));
            float d1 = v.z - mu;
            s1 += exp2_hw(fmaf(d1 * d1, rden2, v.w));
        }
        float s = s0 + s1;

        float incl = scan64(s);
        const float S = bcast_lane(incl, 63);
        const float denom = S * normc + EPS_F;         // ref: sum(probs)+EPS
        const float tt = (u * denom) / normc;

        unsigned long long mgt = __ballot(incl > tt);
        int jstar = mgt ? __builtin_ctzll(mgt) : 64;
        int jj = (jstar < 64) ? jstar : 0;
        float exclb = bcast_lane(incl - s, jj);

        int c = lane & 31;
        float2 al = sP[jj * 32 + c];
        float d = al.x - mu;
        float cum = scan32(exp2_hw(fmaf(d * d, rden2, al.y)));
        cum += exclb;
        unsigned int m2 = (unsigned int)(__ballot(cum > tt) & 0xffffffffULL);
        int sub = m2 ? (int)__builtin_ctz(m2) : 32;
        int idx = (jstar >= 64) ? 0 : min(jj * 32 + sub, NS - 1);

        if (lane == 0) {
            float2 al2 = sP[idx];
            float dd = al2.x - mu;
            float pk = exp2_hw(fmaf(dd * dd, rden2, al2.y)) * normc;
            const double y0 = -0.9999, y1 = 0.9999;
            const double step = (y1 - y0) / 1999.0;
            float gv = (idx == NS - 1) ? (float)y1
                                       : (float)(y0 + (double)idx * step);
            out_vals[elem] = gv;
            out_probs[elem] = pk / denom;              // ref: probs/(sum+EPS)
        }
    }
}

extern "C" void kernel_launch(void* const* d_in, const int* in_sizes, int n_in,
                              void* d_out, int out_size, void* d_ws, size_t ws_size,
                              hipStream_t stream) {
    const float* mean = (const float*)d_in[0];
    const float* stdv = (const float*)d_in[1];
    const float* uni = (const float*)d_in[2];
    float* out = (float*)d_out;
    const int nElem = in_sizes[0];                 // 4096*16 = 65536
    float* out_vals = out;
    float* out_probs = out + nElem;

    char* ws = (char*)d_ws;
    float2* tabT = (float2*)ws;                    // 16 KB
    float2* tab2 = (float2*)(ws + 16384);          // 16 KB
    int* cnt = (int*)(ws + 32768);                 // 16 B slot
    int* list = (int*)(ws + 32768 + 16);           // up to 256 KB

    build_table<<<NPAD / 256, 256, 0, stream>>>(tabT, tab2, cnt);

    analytic_kernel<<<(nElem + 255) / 256, 256, 0, stream>>>(
        mean, stdv, uni, tab2, out_vals, out_probs, list, cnt, nElem);

    fallback_kernel<<<2048, 256, 0, stream>>>(
        mean, stdv, uni, (const float4*)tabT, (const float4*)tab2,
        out_vals, out_probs, list, cnt);
}

// Round 14
// 63.163 us; speedup vs baseline: 1.7577x; 1.1977x over previous
//
#include <hip/hip_runtime.h>
#include <math.h>

#define NS 2000
#define NPAD 2048
#define EPS_F 1.1920928955078125e-07f
#define LOG2E 1.4426950408889634f
#define X0F  -0.9999f
#define HREC 999.64996f            // 1/h, h = 1.9998/1999
#define HF   1.00040020e-3f        // h
#define B8C  2.7842747f            // atanh(-0.9999 + 7.5h), bulk/edge seam
#define SIGM 2.0e-3f               // sigma >= 2*h*cosh^2 => sigma/h_loc >= 2
#define PCELL_MIN 1.0e-4f          // min normalized crossing-cell mass (bulk)
#define FLIP_TOL 0.012f            // max output-1 impact of a +-1 index flip
#define BLOCK 256

// 2^x via v_exp_f32 (named wrapper: __exp2f collides with glibc math.h).
__device__ __forceinline__ float exp2_hw(float x) {
    return __builtin_amdgcn_exp2f(x);
}

// ---------- DPP scan helpers (verified rounds 7-13) ----------
template <int CTRL, int RMASK>
static __device__ __forceinline__ float dpp_add(float x) {
    int t = __builtin_amdgcn_update_dpp(0, __float_as_int(x), CTRL, RMASK, 0xf, true);
    return x + __int_as_float(t);
}
static __device__ __forceinline__ float scan64(float x) {
    x = dpp_add<0x111, 0xf>(x);
    x = dpp_add<0x112, 0xf>(x);
    x = dpp_add<0x114, 0xf>(x);
    x = dpp_add<0x118, 0xf>(x);
    x = dpp_add<0x142, 0xa>(x);   // row_bcast:15 -> rows 1,3
    x = dpp_add<0x143, 0xc>(x);   // row_bcast:31 -> rows 2,3
    return x;
}
static __device__ __forceinline__ float scan32(float x) {
    x = dpp_add<0x111, 0xf>(x);
    x = dpp_add<0x112, 0xf>(x);
    x = dpp_add<0x114, 0xf>(x);
    x = dpp_add<0x118, 0xf>(x);
    x = dpp_add<0x142, 0xa>(x);
    return x;
}
static __device__ __forceinline__ float bcast_lane(float x, int lane_sgpr) {
    return __int_as_float(__builtin_amdgcn_readlane(__float_as_int(x), lane_sgpr));
}

// ---------- scalar special functions ----------
// Phi(t) = 0.5*erfc(-t/sqrt2), erfc via A&S 7.1.26 (|err| <= 1.5e-7 abs).
static __device__ __forceinline__ float cdf01(float t) {
    float z = -t * 0.70710678f;
    float az = fabsf(z);
    float k = 1.0f / fmaf(0.3275911f, az, 1.0f);
    float poly = fmaf(k, 1.061405429f, -1.453152027f);
    poly = fmaf(k, poly, 1.421413741f);
    poly = fmaf(k, poly, -0.284496736f);
    poly = fmaf(k, poly, 0.254829592f);
    poly *= k;
    float e = exp2_hw(-az * az * LOG2E);       // exp(-z^2)
    float erfc_az = poly * e;
    float erfc_z = (z < 0.0f) ? (2.0f - erfc_az) : erfc_az;
    return 0.5f * erfc_z;
}
// Giles single-precision erfinv.
static __device__ __forceinline__ float erfinv_f(float x) {
    float w = -logf(fmaf(-x, x, 1.0f));
    bool c = w < 5.0f;
    float ww = c ? (w - 2.5f) : (sqrtf(w) - 3.0f);
    float p = c ? 2.81022636e-08f : -0.000200214257f;
    p = fmaf(p, ww, c ? 3.43273939e-07f : 0.000100950558f);
    p = fmaf(p, ww, c ? -3.5233877e-06f : 0.00134934322f);
    p = fmaf(p, ww, c ? -4.39150654e-06f : -0.00367342844f);
    p = fmaf(p, ww, c ? 0.00021858087f : 0.00573950773f);
    p = fmaf(p, ww, c ? -0.00125372503f : -0.0076224613f);
    p = fmaf(p, ww, c ? -0.00417768164f : 0.00943887047f);
    p = fmaf(p, ww, c ? 0.246640727f : 1.00167406f);
    p = fmaf(p, ww, c ? 1.50140941f : 2.83297682f);
    return p * x;
}
static __device__ __forceinline__ float cosh2f(float t) {    // cosh^2(|t|)
    float e = exp2_hw(2.8853901f * t);                       // e^{2t}
    float re = __builtin_amdgcn_rcpf(e);
    return 0.25f * (e + 2.0f + re);
}

// (a, lw) of grid cell i, exactly the reference/table formulas:
// a = 0.5*logf((1+x)/(1-x)+EPS), lw = log2f(1/(1-x^2)); x from f64 linspace.
// For compile-time i this constant-folds entirely.
static __device__ __forceinline__ float2 cellAL(int i) {
    const double y0 = -0.9999, y1 = 0.9999;
    const double step = (y1 - y0) / 1999.0;
    float x = (i == NS - 1) ? (float)y1 : (float)(y0 + (double)i * step);
    float ratio = (1.0f + x) / (1.0f - x) + EPS_F;
    float a = 0.5f * logf(ratio);
    float lw = log2f(1.0f / (1.0f - x * x));
    return make_float2(a, lw);
}

// ---------- single fused kernel ----------
// Phase 1 (per thread, r13 math verbatim): hybrid analytic inverse-CDF.
//   8 coarsest cells each end summed exactly (inline consts); bulk via
//   continuous CDF + guarded erfinv inversion; flip-impact guard.
// Phase 2 (per block): failed elements handled IN-BLOCK by the proven r8
//   wave-per-element exact path against a block-local LDS table.
__global__ __launch_bounds__(BLOCK) void fused_kernel(
    const float* __restrict__ mean, const float* __restrict__ stdv,
    const float* __restrict__ uni,
    float* __restrict__ out_vals, float* __restrict__ out_probs, int nElem) {

    __shared__ float4 sT[NPAD / 2];     // transposed pair view (16 KB)
    __shared__ float4 sPb[NPAD / 2];    // linear view (16 KB)
    __shared__ int fbList[BLOCK];
    __shared__ int fbCnt;

    const int tid = threadIdx.x;
    if (tid == 0) fbCnt = 0;
    __syncthreads();

    const int gid = blockIdx.x * BLOCK + tid;
    if (gid < nElem) {
        const float mu = mean[gid];
        const float sg = stdv[gid] + EPS_F;          // ref: std + EPS
        const float u = uni[gid];
        const float inv_sg = 1.0f / sg;
        const float rd2 = -0.72134752f * inv_sg * inv_sg;   // log2e/(-2 s^2)
        const float nc = 0.39894228f * inv_sg;              // 1/sqrt(2pi s^2)
        const float hn = HF * nc;

        // Exact edge cells (compile-time (a,lw) constants).
        float ql[8];
        float qlow = 0.0f, qhigh = 0.0f;
        #pragma unroll
        for (int c = 0; c < 8; c++) {
            float2 al = cellAL(c);
            float d = al.x - mu;
            ql[c] = exp2_hw(fmaf(d * d, rd2, al.y));
            qlow += ql[c];
            float2 ah = cellAL(NS - 8 + c);
            float dh = ah.x - mu;
            qhigh += exp2_hw(fmaf(dh * dh, rd2, ah.y));
        }

        const float PloB = cdf01((-B8C - mu) * inv_sg);
        const float PhiB = cdf01(( B8C - mu) * inv_sg);
        const float Qbulk = fmaxf(PhiB - PloB, 0.0f) / hn;  // q-units
        const float Stot = qlow + Qbulk + qhigh;
        const float denomP = fmaf(nc, Stot, EPS_F);         // sum(probs)+EPS
        const float tt = u * denomP / nc;                   // target, q-units

        // Seam/peak fine-ness guard; high-edge/no-crossing -> fallback.
        bool ok = (sg >= SIGM * cosh2f(fminf(fabsf(mu), B8C)));
        ok = ok && (tt < qlow + Qbulk);

        int idx = -1;
        float qsel = 0.0f;

        // Low-edge exact walk.
        {
            float cum = 0.0f;
            #pragma unroll
            for (int c = 0; c < 8; c++) {
                cum += ql[c];
                if (idx < 0 && cum > tt) { idx = c; qsel = ql[c]; }
            }
        }
        if (ok && idx < 0) {
            // Bulk inversion: Phi_target -> a* -> x index.
            float Pt = fmaf(tt - qlow, hn, PloB);
            float xx = fmaf(2.0f, Pt, -1.0f);
            xx = fminf(fmaxf(xx, -0.99999994f), 0.99999994f);
            float ts = 1.41421356f * erfinv_f(xx);
            float as = fmaf(sg, ts, mu);
            float e2 = exp2_hw(as * 2.8853901f);         // e^{2a*}
            float tau = 1.0f - 2.0f / (e2 + 1.0f);       // tanh(a*)
            float fi = fmaf(tau - X0F, HREC, -0.5f);
            int is = (int)floorf(fi) + 1;
            ok = ok && (is >= 8) && (is <= 1991)
                    && (sg >= SIGM * cosh2f(fabsf(as)));
            is = min(max(is, 8), 1991);
            float2 al = cellAL(is);
            float d = al.x - mu;
            float qi = exp2_hw(fmaf(d * d, rd2, al.y));
            float pn = nc * qi / denomP;                 // normalized cell mass
            ok = ok && (pn >= PCELL_MIN);                // inversion stability
            // Flip-impact guard: +-1 index flip moves output-1 <= FLIP_TOL.
            float hl = HF * cosh2f(fabsf(as));           // local a-spacing
            float r = hl * inv_sg;
            float arg = r * (fabsf(as - mu) * inv_sg + 0.5f * r);
            float ratio = exp2_hw(LOG2E * fminf(arg, 20.0f)) - 1.0f;
            ok = ok && (pn * ratio <= FLIP_TOL);
            if (ok) { idx = is; qsel = qi; }
        }

        if (ok && idx >= 0) {
            const double y0 = -0.9999, y1 = 0.9999;
            const double step = (y1 - y0) / 1999.0;
            float gv = (idx == NS - 1) ? (float)y1
                                       : (float)(y0 + (double)idx * step);
            out_vals[gid] = gv;
            out_probs[gid] = nc * qsel / denomP;         // ref: p/(sum+EPS)
        } else {
            int s = atomicAdd(&fbCnt, 1);
            fbList[s] = tid;
        }
    }
    __syncthreads();
    const int cnt = fbCnt;
    if (cnt == 0) return;                                // block-uniform

    // ---- build block-local LDS tables (bit-identical to r13's) ----
    {
        float2* sP2 = (float2*)sPb;
        float2* sT2 = (float2*)sT;
        #pragma unroll
        for (int r = 0; r < 8; r++) {
            int i = tid * 8 + r;
            float2 alw = (i < NS) ? cellAL(i) : make_float2(0.0f, -1000.0f);
            sP2[i] = alw;
            int l = i >> 5, k = i & 31, kk = k >> 1, h = k & 1;
            sT2[(kk * 64 + l) * 2 + h] = alw;
        }
    }
    __syncthreads();

    // ---- exact wave-per-element fallback (r8 path, in-block list) ----
    const float2* sP = (const float2*)sPb;
    const int lane = tid & 63;
    const int wid = tid >> 6;
    for (int slot = wid; slot < cnt; slot += 4) {
        const int elem = blockIdx.x * BLOCK + fbList[slot];
        const float mu = mean[elem];
        const float sg = stdv[elem] + EPS_F;           // ref: std + EPS
        const float u = uni[elem];
        const float sg2 = sg * sg;
        const float rden2 = LOG2E / (-2.0f * sg2);
        const float normc = 1.0f / sqrtf(6.2831853071795864f * sg2);

        float s0 = 0.0f, s1 = 0.0f;
        #pragma unroll
        for (int kk = 0; kk < 16; kk++) {
            float4 v = sT[kk * 64 + lane];             // (a0,lw0,a1,lw1)
            float d0 = v.x - mu;
            s0 += exp2_hw(fmaf(d0 * d0, rden2, v.y));
            float d1 = v.z - mu;
            s1 += exp2_hw(fmaf(d1 * d1, rden2, v.w));
        }
        float s = s0 + s1;

        float incl = scan64(s);
        const float S = bcast_lane(incl, 63);
        const float denom = S * normc + EPS_F;         // ref: sum(probs)+EPS
        const float tt = (u * denom) / normc;

        unsigned long long mgt = __ballot(incl > tt);
        int jstar = mgt ? __builtin_ctzll(mgt) : 64;
        int jj = (jstar < 64) ? jstar : 0;
        float exclb = bcast_lane(incl - s, jj);

        int c = lane & 31;
        float2 al = sP[jj * 32 + c];
        float d = al.x - mu;
        float cum = scan32(exp2_hw(fmaf(d * d, rden2, al.y)));
        cum += exclb;
        unsigned int m2 = (unsigned int)(__ballot(cum > tt) & 0xffffffffULL);
        int sub = m2 ? (int)__builtin_ctz(m2) : 32;
        int idx = (jstar >= 64) ? 0 : min(jj * 32 + sub, NS - 1);

        if (lane == 0) {
            float2 al2 = sP[idx];
            float dd = al2.x - mu;
            float pk = exp2_hw(fmaf(dd * dd, rden2, al2.y)) * normc;
            const double y0 = -0.9999, y1 = 0.9999;
            const double step = (y1 - y0) / 1999.0;
            float gv = (idx == NS - 1) ? (float)y1
                                       : (float)(y0 + (double)idx * step);
            out_vals[elem] = gv;
            out_probs[elem] = pk / denom;              // ref: probs/(sum+EPS)
        }
    }
}

extern "C" void kernel_launch(void* const* d_in, const int* in_sizes, int n_in,
                              void* d_out, int out_size, void* d_ws, size_t ws_size,
                              hipStream_t stream) {
    const float* mean = (const float*)d_in[0];
    const float* stdv = (const float*)d_in[1];
    const float* uni = (const float*)d_in[2];
    float* out = (float*)d_out;
    const int nElem = in_sizes[0];                 // 4096*16 = 65536
    float* out_vals = out;
    float* out_probs = out + nElem;
    (void)d_ws; (void)ws_size;

    const int grid = (nElem + BLOCK - 1) / BLOCK;  // 256 blocks
    fused_kernel<<<grid, BLOCK, 0, stream>>>(mean, stdv, uni,
                                             out_vals, out_probs, nElem);
}